// Round 2
// baseline (286.065 us; speedup 1.0000x reference)
//
#include <hip/hip_runtime.h>
#include <hip/hip_bf16.h>
#include <stdint.h>

#define NEGV -1e30f

typedef __attribute__((ext_vector_type(8))) __bf16 bf16x8;
typedef __attribute__((ext_vector_type(4))) float f32x4;

__device__ __forceinline__ uint16_t f2bfu(float f){
  __hip_bfloat16 h = __float2bfloat16(f);
  return *reinterpret_cast<const uint16_t*>(&h);
}

// ---------------- child = relu(x @ W_parent + b_parent) -> cf (fp32), cfc slot 0
__global__ __launch_bounds__(256) void k_child(
    const float* __restrict__ pf, const float* __restrict__ gc,
    const float* __restrict__ gn, const float* __restrict__ Wp,
    const float* __restrict__ bp, float* __restrict__ cf, float* __restrict__ cfc)
{
  __shared__ float xs[282];
  int tid = threadIdx.x;
  for (int i = tid; i < 282; i += 256){
    float v;
    if (i < 256) v = pf[i];
    else if (i < 272) v = gc[i-256];
    else v = gn[i-272];
    xs[i] = v;
  }
  __syncthreads();
  int j = blockIdx.x*256 + tid;
  float acc = bp[j];
  for (int i = 0; i < 282; ++i) acc = fmaf(xs[i], Wp[i*65536+j], acc);
  acc = fmaxf(acc, 0.f);
  cf[j] = acc;
  cfc[(j>>8)*768 + (j&255)] = acc;
}

// ---------------- exists logits + node_ok + zero has_edges flag
__global__ __launch_bounds__(256) void k_exists(
  const float* __restrict__ cf, const float* __restrict__ Wex,
  const float* __restrict__ bex, float* __restrict__ exout,
  int* __restrict__ ok, int* __restrict__ flag)
{
  __shared__ float red[256];
  int m = blockIdx.x, tid = threadIdx.x;
  red[tid] = cf[m*256+tid]*Wex[tid];
  __syncthreads();
  for (int s = 128; s > 0; s >>= 1){ if (tid < s) red[tid] += red[tid+s]; __syncthreads(); }
  if (tid == 0){
    float logit = red[0] + bex[0];
    exout[m] = logit;
    ok[m] = logit > 0.f ? 1 : 0;
    if (m == 0) *flag = 0;
  }
}

// ---------------- a = cf@W_el[:H], b2 = cf@W_el[H:]
__global__ __launch_bounds__(256) void k_ab(
  const float* __restrict__ cf, const float* __restrict__ Wel,
  float* __restrict__ a, float* __restrict__ b2)
{
  __shared__ float cfs[256];
  int bid = blockIdx.x; int sel = bid >> 8; int m = bid & 255; int tid = threadIdx.x;
  cfs[tid] = cf[m*256+tid];
  __syncthreads();
  const float* W = Wel + sel*65536;
  float acc = 0.f;
  for (int k = 0; k < 256; ++k) acc = fmaf(cfs[k], W[k*256+tid], acc);
  (sel ? b2 : a)[m*256+tid] = acc;
}

// ---------------- ee (output) + eemask (mask folded as -1e30 sentinel) + has_edges
__global__ __launch_bounds__(256) void k_ee(
  const float* __restrict__ a, const float* __restrict__ b2,
  const float* __restrict__ bel, const float* __restrict__ Wee,
  const float* __restrict__ bee, const int* __restrict__ ok,
  float* __restrict__ eemask, float* __restrict__ eeout, int* __restrict__ flag)
{
  __shared__ float wee[1024];
  __shared__ float ac[256];
  int m = blockIdx.x, tid = threadIdx.x;
  for (int i = tid; i < 1024; i += 256) wee[i] = Wee[i];
  ac[tid] = a[m*256+tid] + bel[tid];
  __syncthreads();
  int n = tid;
  float e0 = bee[0], e1 = bee[1], e2 = bee[2], e3 = bee[3];
  const float* b2r = b2 + n*256;
  for (int h = 0; h < 256; ++h){
    float el = fmaxf(ac[h] + b2r[h], 0.f);
    e0 = fmaf(el, wee[h], e0);
    e1 = fmaf(el, wee[256+h], e1);
    e2 = fmaf(el, wee[512+h], e2);
    e3 = fmaf(el, wee[768+h], e3);
  }
  int idx = (m*256+n)*4;
  f32x4 eo; eo[0]=e0; eo[1]=e1; eo[2]=e2; eo[3]=e3;
  *reinterpret_cast<f32x4*>(eeout + idx) = eo;
  int okmn = ok[m] & ok[n];
  f32x4 em;
  em[0] = (okmn && e0 > 0.f) ? e0 : NEGV;
  em[1] = (okmn && e1 > 0.f) ? e1 : NEGV;
  em[2] = (okmn && e2 > 0.f) ? e2 : NEGV;
  em[3] = (okmn && e3 > 0.f) ? e3 : NEGV;
  *reinterpret_cast<f32x4*>(eemask + idx) = em;
  if (em[0] > -1e29f || em[1] > -1e29f || em[2] > -1e29f || em[3] > -1e29f) atomicOr(flag, 1);
}

// ---------------- WeT[it][k][h] = bf16(W_ne[it][512+h][k])  (transpose for MFMA B-frags)
__global__ __launch_bounds__(256) void k_wet(const float* __restrict__ Wne,
                                             __hip_bfloat16* __restrict__ WeT)
{
  int bid = blockIdx.x; int i = bid >> 8, k = bid & 255, h = threadIdx.x;
  WeT[i*65536 + k*256 + h] = __float2bfloat16(Wne[i*197632 + (512+h)*256 + k]);
}

// ---------------- s'[m,k]=cf@Ws + b_ne ; d[n,k]=cf@Wd
__global__ __launch_bounds__(256) void k_sd(
  const float* __restrict__ cf, const float* __restrict__ Wne,
  const float* __restrict__ bne, float* __restrict__ sp, float* __restrict__ d, int it)
{
  __shared__ float cfs[256];
  int bid = blockIdx.x; int sel = bid >> 8; int m = bid & 255; int tid = threadIdx.x;
  cfs[tid] = cf[m*256+tid];
  __syncthreads();
  const float* W = Wne + it*197632 + sel*65536;
  float acc = sel ? 0.f : bne[it*256+tid];
  for (int h = 0; h < 256; ++h) acc = fmaf(cfs[h], W[h*256+tid], acc);
  (sel ? d : sp)[m*256+tid] = acc;
}

// ---------------- fused per-iteration: recompute el chunk -> MFMA E=el@We -> masked max
// one block per m; wave w owns k in [64w, 64w+64)
__global__ __launch_bounds__(256,1) void k_fused(
  const float* __restrict__ a, const float* __restrict__ bel,
  const float* __restrict__ b2, const __hip_bfloat16* __restrict__ wet,
  const float* __restrict__ sp, const float* __restrict__ dmat,
  const float* __restrict__ eemask, const float* __restrict__ Wne_it,
  float* __restrict__ cf, float* __restrict__ cfc, const int* __restrict__ flag, int it)
{
  __shared__ float ac[256];
  int m = blockIdx.x; int tid = threadIdx.x;
  ac[tid] = a[m*256+tid] + bel[tid];
  __syncthreads();
  int w = tid >> 6, l = tid & 63, l15 = l & 15, lg = l >> 4;

  // B-frags (We, k-major transposed): resident for the whole block
  bf16x8 Bf[4][8];
  #pragma unroll
  for (int kt = 0; kt < 4; ++kt){
    int krow = (w*4+kt)*16 + l15;
    #pragma unroll
    for (int kk = 0; kk < 8; ++kk)
      Bf[kt][kk] = *reinterpret_cast<const bf16x8*>(wet + krow*256 + kk*32 + lg*8);
  }
  float spv[4], wtv[4][4];
  #pragma unroll
  for (int kt = 0; kt < 4; ++kt){
    int kcol = (w*4+kt)*16 + l15;
    spv[kt] = sp[m*256+kcol];
    #pragma unroll
    for (int t = 0; t < 4; ++t) wtv[t][kt] = Wne_it[(768+t)*256 + kcol];
  }
  float runmax[4] = {NEGV, NEGV, NEGV, NEGV};

  for (int n0 = 0; n0 < 256; n0 += 16){
    // A-frags: el[n0+l15][kk*32+lg*8 .. +8] computed in-register
    bf16x8 Af[8];
    int nA = n0 + l15;
    const float* b2r = b2 + nA*256;
    #pragma unroll
    for (int kk = 0; kk < 8; ++kk){
      int h0 = kk*32 + lg*8;
      f32x4 bb0 = *reinterpret_cast<const f32x4*>(b2r + h0);
      f32x4 bb1 = *reinterpret_cast<const f32x4*>(b2r + h0 + 4);
      f32x4 aa0 = *reinterpret_cast<const f32x4*>(ac + h0);
      f32x4 aa1 = *reinterpret_cast<const f32x4*>(ac + h0 + 4);
      union { uint16_t u[8]; bf16x8 v; } fr;
      #pragma unroll
      for (int j = 0; j < 4; ++j){
        fr.u[j]   = f2bfu(fmaxf(aa0[j]+bb0[j], 0.f));
        fr.u[j+4] = f2bfu(fmaxf(aa1[j]+bb1[j], 0.f));
      }
      Af[kk] = fr.v;
    }
    f32x4 acc0 = {0,0,0,0}, acc1 = {0,0,0,0}, acc2 = {0,0,0,0}, acc3 = {0,0,0,0};
    #pragma unroll
    for (int kk = 0; kk < 8; ++kk){
      acc0 = __builtin_amdgcn_mfma_f32_16x16x32_bf16(Af[kk], Bf[0][kk], acc0, 0, 0, 0);
      acc1 = __builtin_amdgcn_mfma_f32_16x16x32_bf16(Af[kk], Bf[1][kk], acc1, 0, 0, 0);
      acc2 = __builtin_amdgcn_mfma_f32_16x16x32_bf16(Af[kk], Bf[2][kk], acc2, 0, 0, 0);
      acc3 = __builtin_amdgcn_mfma_f32_16x16x32_bf16(Af[kk], Bf[3][kk], acc3, 0, 0, 0);
    }
    // D layout: col = l&15 (k), row = (l>>4)*4 + reg (n_local)
    #pragma unroll
    for (int r = 0; r < 4; ++r){
      int n = n0 + lg*4 + r;
      f32x4 me = *reinterpret_cast<const f32x4*>(eemask + (m*256+n)*4);
      const float* dr = dmat + n*256;
      float Ed0 = acc0[r] + dr[w*64 +      l15] + spv[0];
      float Ed1 = acc1[r] + dr[w*64 + 16 + l15] + spv[1];
      float Ed2 = acc2[r] + dr[w*64 + 32 + l15] + spv[2];
      float Ed3 = acc3[r] + dr[w*64 + 48 + l15] + spv[3];
      #pragma unroll
      for (int t = 0; t < 4; ++t){
        if (me[t] > -1e29f){
          runmax[0] = fmaxf(runmax[0], fmaf(me[t], wtv[t][0], Ed0));
          runmax[1] = fmaxf(runmax[1], fmaf(me[t], wtv[t][1], Ed1));
          runmax[2] = fmaxf(runmax[2], fmaf(me[t], wtv[t][2], Ed2));
          runmax[3] = fmaxf(runmax[3], fmaf(me[t], wtv[t][3], Ed3));
        }
      }
    }
  }
  int he = *flag;
  #pragma unroll
  for (int kt = 0; kt < 4; ++kt){
    float v = runmax[kt];
    v = fmaxf(v, __shfl_xor(v, 16));
    v = fmaxf(v, __shfl_xor(v, 32));
    if (l < 16){
      int kcol = w*64 + kt*16 + l;
      float nv = fmaxf(v, 0.f);
      float outv = he ? nv : cf[m*256+kcol];
      cf[m*256+kcol] = outv;
      cfc[m*768 + 256*(it+1) + kcol] = outv;
    }
  }
}

// ---------------- ch = relu(cfc@W_child+b); feats = relu(ch@W_child2+b); sem = ch@W_sem+b
__global__ __launch_bounds__(256) void k_final(
  const float* __restrict__ cfc, const float* __restrict__ Wch,
  const float* __restrict__ bch, const float* __restrict__ Wsem,
  const float* __restrict__ bsem, const float* __restrict__ Wc2,
  const float* __restrict__ bc2, float* __restrict__ feats_out,
  float* __restrict__ sem_out)
{
  __shared__ float row[768];
  __shared__ float ch[256];
  int m = blockIdx.x, tid = threadIdx.x;
  row[tid]     = cfc[m*768+tid];
  row[tid+256] = cfc[m*768+256+tid];
  row[tid+512] = cfc[m*768+512+tid];
  __syncthreads();
  float acc = bch[tid];
  for (int j = 0; j < 768; ++j) acc = fmaf(row[j], Wch[j*256+tid], acc);
  ch[tid] = fmaxf(acc, 0.f);
  __syncthreads();
  float f = bc2[tid];
  float s = (tid < 50) ? bsem[tid] : 0.f;
  for (int k = 0; k < 256; ++k){
    float c = ch[k];
    f = fmaf(c, Wc2[k*256+tid], f);
    if (tid < 50) s = fmaf(c, Wsem[k*50+tid], s);
  }
  feats_out[m*256+tid] = fmaxf(f, 0.f);
  if (tid < 50) sem_out[m*50+tid] = s;
}

extern "C" void kernel_launch(void* const* d_in, const int* in_sizes, int n_in,
                              void* d_out, int out_size, void* d_ws, size_t ws_size,
                              hipStream_t stream)
{
  const float* pf  = (const float*)d_in[0];
  const float* gc  = (const float*)d_in[1];
  const float* gn  = (const float*)d_in[2];
  const float* Wp  = (const float*)d_in[3];
  const float* bp  = (const float*)d_in[4];
  const float* Wex = (const float*)d_in[5];
  const float* bex = (const float*)d_in[6];
  const float* Wsem= (const float*)d_in[7];
  const float* bsem= (const float*)d_in[8];
  const float* Wel = (const float*)d_in[9];
  const float* bel = (const float*)d_in[10];
  const float* Wee = (const float*)d_in[11];
  const float* bee = (const float*)d_in[12];
  const float* Wne = (const float*)d_in[13];
  const float* bne = (const float*)d_in[14];
  const float* Wch = (const float*)d_in[15];
  const float* bch = (const float*)d_in[16];
  const float* Wc2 = (const float*)d_in[17];
  const float* bc2 = (const float*)d_in[18];

  float* out = (float*)d_out;
  float* feats_out = out;             // 65536
  float* sem_out   = out + 65536;     // 12800
  float* ex_out    = out + 78336;     // 256
  float* ee_out    = out + 78592;     // 262144

  char* ws = (char*)d_ws;
  float* cf    = (float*)(ws);
  float* cfc   = (float*)(ws + (256u<<10));
  float* a_    = (float*)(ws + (1024u<<10));
  float* b2_   = (float*)(ws + (1280u<<10));
  float* sp_   = (float*)(ws + (1536u<<10));
  float* dmat  = (float*)(ws + (1792u<<10));
  float* eem   = (float*)(ws + (2048u<<10));
  __hip_bfloat16* WeT = (__hip_bfloat16*)(ws + (3072u<<10));
  int* ok   = (int*)(ws + (3328u<<10));
  int* flag = ok + 256;

  k_child<<<256,256,0,stream>>>(pf,gc,gn,Wp,bp,cf,cfc);
  k_exists<<<256,256,0,stream>>>(cf,Wex,bex,ex_out,ok,flag);
  k_ab<<<512,256,0,stream>>>(cf,Wel,a_,b2_);
  k_ee<<<256,256,0,stream>>>(a_,b2_,bel,Wee,bee,ok,eem,ee_out,flag);
  k_wet<<<512,256,0,stream>>>(Wne,WeT);
  for (int it = 0; it < 2; ++it){
    k_sd<<<512,256,0,stream>>>(cf,Wne,bne,sp_,dmat,it);
    k_fused<<<256,256,0,stream>>>(a_,bel,b2_,WeT + it*65536,sp_,dmat,eem,
                                  Wne + it*197632,cf,cfc,flag,it);
  }
  k_final<<<256,256,0,stream>>>(cfc,Wch,bch,Wsem,bsem,Wc2,bc2,feats_out,sem_out);
}

// Round 3
// 259.474 us; speedup vs baseline: 1.1025x; 1.1025x over previous
//
#include <hip/hip_runtime.h>
#include <hip/hip_bf16.h>
#include <stdint.h>

#define NEGV -1e30f

typedef __attribute__((ext_vector_type(8))) __bf16 bf16x8;
typedef __attribute__((ext_vector_type(4))) float f32x4;

__device__ __forceinline__ uint16_t f2bfu(float f){
  __hip_bfloat16 h = __float2bfloat16(f);
  return *reinterpret_cast<const uint16_t*>(&h);
}

// ---------------- child = relu(x @ W_parent + b_parent) -> cf (fp32), cfcb slot 0 (bf16)
__global__ __launch_bounds__(256) void k_child(
    const float* __restrict__ pf, const float* __restrict__ gc,
    const float* __restrict__ gn, const float* __restrict__ Wp,
    const float* __restrict__ bp, float* __restrict__ cf, __hip_bfloat16* __restrict__ cfcb)
{
  __shared__ float xs[282];
  int tid = threadIdx.x;
  for (int i = tid; i < 282; i += 256){
    float v;
    if (i < 256) v = pf[i];
    else if (i < 272) v = gc[i-256];
    else v = gn[i-272];
    xs[i] = v;
  }
  __syncthreads();
  int j = blockIdx.x*256 + tid;
  float acc = bp[j];
  #pragma unroll 4
  for (int i = 0; i < 282; ++i) acc = fmaf(xs[i], Wp[i*65536+j], acc);
  acc = fmaxf(acc, 0.f);
  cf[j] = acc;
  cfcb[(j>>8)*768 + (j&255)] = __float2bfloat16(acc);
}

// ---------------- exists logits + node_ok + zero has_edges flag
__global__ __launch_bounds__(256) void k_exists(
  const float* __restrict__ cf, const float* __restrict__ Wex,
  const float* __restrict__ bex, float* __restrict__ exout,
  int* __restrict__ ok, int* __restrict__ flag)
{
  __shared__ float red[256];
  int m = blockIdx.x, tid = threadIdx.x;
  red[tid] = cf[m*256+tid]*Wex[tid];
  __syncthreads();
  for (int s = 128; s > 0; s >>= 1){ if (tid < s) red[tid] += red[tid+s]; __syncthreads(); }
  if (tid == 0){
    float logit = red[0] + bex[0];
    exout[m] = logit;
    ok[m] = logit > 0.f ? 1 : 0;
    if (m == 0) *flag = 0;
  }
}

// ---------------- a = cf@W_el[:H], b2 = cf@W_el[H:]  (fp32, row-blocked RB=4; also writes b2T)
__global__ __launch_bounds__(256) void k_ab(
  const float* __restrict__ cf, const float* __restrict__ Wel,
  float* __restrict__ a, float* __restrict__ b2, float* __restrict__ b2T)
{
  __shared__ float cfs[4][256];
  int bid = blockIdx.x; int sel = bid >> 6; int m0 = (bid & 63)*4; int tid = threadIdx.x;
  #pragma unroll
  for (int r = 0; r < 4; ++r) cfs[r][tid] = cf[(m0+r)*256 + tid];
  __syncthreads();
  const float* W = Wel + sel*65536;
  float acc0 = 0.f, acc1 = 0.f, acc2 = 0.f, acc3 = 0.f;
  #pragma unroll 8
  for (int j = 0; j < 256; ++j){
    float w = W[j*256+tid];
    acc0 = fmaf(cfs[0][j], w, acc0);
    acc1 = fmaf(cfs[1][j], w, acc1);
    acc2 = fmaf(cfs[2][j], w, acc2);
    acc3 = fmaf(cfs[3][j], w, acc3);
  }
  float* dst = sel ? b2 : a;
  dst[(m0+0)*256+tid] = acc0;
  dst[(m0+1)*256+tid] = acc1;
  dst[(m0+2)*256+tid] = acc2;
  dst[(m0+3)*256+tid] = acc3;
  if (sel){
    b2T[tid*256 + m0+0] = acc0;
    b2T[tid*256 + m0+1] = acc1;
    b2T[tid*256 + m0+2] = acc2;
    b2T[tid*256 + m0+3] = acc3;
  }
}

// ---------------- ee (output) + eemask (mask folded as -1e30 sentinel) + has_edges
// b2T gives coalesced loads: lane n reads b2T[h*256+n]
__global__ __launch_bounds__(256) void k_ee(
  const float* __restrict__ a, const float* __restrict__ b2T,
  const float* __restrict__ bel, const float* __restrict__ Wee,
  const float* __restrict__ bee, const int* __restrict__ ok,
  float* __restrict__ eemask, float* __restrict__ eeout, int* __restrict__ flag)
{
  __shared__ float wee[1024];
  __shared__ float ac[256];
  int m = blockIdx.x, tid = threadIdx.x;
  for (int i = tid; i < 1024; i += 256) wee[i] = Wee[i];
  ac[tid] = a[m*256+tid] + bel[tid];
  __syncthreads();
  int n = tid;
  float e0 = bee[0], e1 = bee[1], e2 = bee[2], e3 = bee[3];
  #pragma unroll 8
  for (int h = 0; h < 256; ++h){
    float el = fmaxf(ac[h] + b2T[h*256+n], 0.f);
    e0 = fmaf(el, wee[h], e0);
    e1 = fmaf(el, wee[256+h], e1);
    e2 = fmaf(el, wee[512+h], e2);
    e3 = fmaf(el, wee[768+h], e3);
  }
  int idx = (m*256+n)*4;
  f32x4 eo; eo[0]=e0; eo[1]=e1; eo[2]=e2; eo[3]=e3;
  *reinterpret_cast<f32x4*>(eeout + idx) = eo;
  int okmn = ok[m] & ok[n];
  f32x4 em;
  em[0] = (okmn && e0 > 0.f) ? e0 : NEGV;
  em[1] = (okmn && e1 > 0.f) ? e1 : NEGV;
  em[2] = (okmn && e2 > 0.f) ? e2 : NEGV;
  em[3] = (okmn && e3 > 0.f) ? e3 : NEGV;
  *reinterpret_cast<f32x4*>(eemask + idx) = em;
  if (em[0] > -1e29f || em[1] > -1e29f || em[2] > -1e29f || em[3] > -1e29f) atomicOr(flag, 1);
}

// ---------------- WeT[it][k][h] = bf16(W_ne[it][512+h][k])  (transpose for MFMA B-frags)
__global__ __launch_bounds__(256) void k_wet(const float* __restrict__ Wne,
                                             __hip_bfloat16* __restrict__ WeT)
{
  int bid = blockIdx.x; int i = bid >> 8, k = bid & 255, h = threadIdx.x;
  WeT[i*65536 + k*256 + h] = __float2bfloat16(Wne[i*197632 + (512+h)*256 + k]);
}

// ---------------- tiled fp32 -> bf16 transpose: out[N][K] = bf16(in[K][N]), 64x64 tiles
__global__ __launch_bounds__(256) void k_transpose_bf16(
  const float* __restrict__ in, __hip_bfloat16* __restrict__ out, int K, int N, int ktiles)
{
  __shared__ float t[64][65];
  int kt = blockIdx.x % ktiles, nt = blockIdx.x / ktiles;
  int k0 = kt*64, n0 = nt*64;
  int tid = threadIdx.x; int c = tid & 63, rg = tid >> 6;
  #pragma unroll
  for (int rr = 0; rr < 16; ++rr){
    int row = rg + rr*4;
    t[row][c] = in[(k0+row)*N + n0 + c];
  }
  __syncthreads();
  #pragma unroll
  for (int rr = 0; rr < 16; ++rr){
    int row = rg + rr*4;
    out[(n0+row)*K + k0 + c] = __float2bfloat16(t[c][row]);
  }
}

// ---------------- WsemT[64][256]: WsemT[c][j] = bf16(Wsem[j][c]) (pad c>=50 with 0)
__global__ __launch_bounds__(256) void k_wsem(const float* __restrict__ Wsem,
                                              __hip_bfloat16* __restrict__ WsemT)
{
  int tid = threadIdx.x;
  int j = blockIdx.x*4 + (tid>>6), c = tid & 63;
  float v = (c < 50) ? Wsem[j*50+c] : 0.f;
  WsemT[c*256 + j] = __float2bfloat16(v);
}

// ---------------- s'[m,k]=cf@Ws + b_ne ; d[n,k]=cf@Wd  (fp32, row-blocked RB=4)
__global__ __launch_bounds__(256) void k_sd(
  const float* __restrict__ cf, const float* __restrict__ Wne,
  const float* __restrict__ bne, float* __restrict__ sp, float* __restrict__ d, int it)
{
  __shared__ float cfs[4][256];
  int bid = blockIdx.x; int sel = bid >> 6; int m0 = (bid & 63)*4; int tid = threadIdx.x;
  #pragma unroll
  for (int r = 0; r < 4; ++r) cfs[r][tid] = cf[(m0+r)*256 + tid];
  __syncthreads();
  const float* W = Wne + it*197632 + sel*65536;
  float bias = sel ? 0.f : bne[it*256+tid];
  float acc0 = bias, acc1 = bias, acc2 = bias, acc3 = bias;
  #pragma unroll 8
  for (int j = 0; j < 256; ++j){
    float w = W[j*256+tid];
    acc0 = fmaf(cfs[0][j], w, acc0);
    acc1 = fmaf(cfs[1][j], w, acc1);
    acc2 = fmaf(cfs[2][j], w, acc2);
    acc3 = fmaf(cfs[3][j], w, acc3);
  }
  float* dst = sel ? d : sp;
  dst[(m0+0)*256+tid] = acc0;
  dst[(m0+1)*256+tid] = acc1;
  dst[(m0+2)*256+tid] = acc2;
  dst[(m0+3)*256+tid] = acc3;
}

// ---------------- fused per-iteration: recompute el chunk -> MFMA E=el@We -> masked max
// one block per m; wave w owns k in [64w, 64w+64)
__global__ __launch_bounds__(256,1) void k_fused(
  const float* __restrict__ a, const float* __restrict__ bel,
  const float* __restrict__ b2, const __hip_bfloat16* __restrict__ wet,
  const float* __restrict__ sp, const float* __restrict__ dmat,
  const float* __restrict__ eemask, const float* __restrict__ Wne_it,
  float* __restrict__ cf, __hip_bfloat16* __restrict__ cfcb, const int* __restrict__ flag, int it)
{
  __shared__ float ac[256];
  int m = blockIdx.x; int tid = threadIdx.x;
  ac[tid] = a[m*256+tid] + bel[tid];
  __syncthreads();
  int w = tid >> 6, l = tid & 63, l15 = l & 15, lg = l >> 4;

  // B-frags (We, k-major transposed): resident for the whole block
  bf16x8 Bf[4][8];
  #pragma unroll
  for (int kt = 0; kt < 4; ++kt){
    int krow = (w*4+kt)*16 + l15;
    #pragma unroll
    for (int kk = 0; kk < 8; ++kk)
      Bf[kt][kk] = *reinterpret_cast<const bf16x8*>(wet + krow*256 + kk*32 + lg*8);
  }
  float spv[4], wtv[4][4];
  #pragma unroll
  for (int kt = 0; kt < 4; ++kt){
    int kcol = (w*4+kt)*16 + l15;
    spv[kt] = sp[m*256+kcol];
    #pragma unroll
    for (int t = 0; t < 4; ++t) wtv[t][kt] = Wne_it[(768+t)*256 + kcol];
  }
  float runmax[4] = {NEGV, NEGV, NEGV, NEGV};

  for (int n0 = 0; n0 < 256; n0 += 16){
    // A-frags: el[n0+l15][kk*32+lg*8 .. +8] computed in-register
    bf16x8 Af[8];
    int nA = n0 + l15;
    const float* b2r = b2 + nA*256;
    #pragma unroll
    for (int kk = 0; kk < 8; ++kk){
      int h0 = kk*32 + lg*8;
      f32x4 bb0 = *reinterpret_cast<const f32x4*>(b2r + h0);
      f32x4 bb1 = *reinterpret_cast<const f32x4*>(b2r + h0 + 4);
      f32x4 aa0 = *reinterpret_cast<const f32x4*>(ac + h0);
      f32x4 aa1 = *reinterpret_cast<const f32x4*>(ac + h0 + 4);
      union { uint16_t u[8]; bf16x8 v; } fr;
      #pragma unroll
      for (int j = 0; j < 4; ++j){
        fr.u[j]   = f2bfu(fmaxf(aa0[j]+bb0[j], 0.f));
        fr.u[j+4] = f2bfu(fmaxf(aa1[j]+bb1[j], 0.f));
      }
      Af[kk] = fr.v;
    }
    f32x4 acc0 = {0,0,0,0}, acc1 = {0,0,0,0}, acc2 = {0,0,0,0}, acc3 = {0,0,0,0};
    #pragma unroll
    for (int kk = 0; kk < 8; ++kk){
      acc0 = __builtin_amdgcn_mfma_f32_16x16x32_bf16(Af[kk], Bf[0][kk], acc0, 0, 0, 0);
      acc1 = __builtin_amdgcn_mfma_f32_16x16x32_bf16(Af[kk], Bf[1][kk], acc1, 0, 0, 0);
      acc2 = __builtin_amdgcn_mfma_f32_16x16x32_bf16(Af[kk], Bf[2][kk], acc2, 0, 0, 0);
      acc3 = __builtin_amdgcn_mfma_f32_16x16x32_bf16(Af[kk], Bf[3][kk], acc3, 0, 0, 0);
    }
    // D layout: col = l&15 (k), row = (l>>4)*4 + reg (n_local)
    #pragma unroll
    for (int r = 0; r < 4; ++r){
      int n = n0 + lg*4 + r;
      f32x4 me = *reinterpret_cast<const f32x4*>(eemask + (m*256+n)*4);
      const float* dr = dmat + n*256;
      float Ed0 = acc0[r] + dr[w*64 +      l15] + spv[0];
      float Ed1 = acc1[r] + dr[w*64 + 16 + l15] + spv[1];
      float Ed2 = acc2[r] + dr[w*64 + 32 + l15] + spv[2];
      float Ed3 = acc3[r] + dr[w*64 + 48 + l15] + spv[3];
      #pragma unroll
      for (int t = 0; t < 4; ++t){
        if (me[t] > -1e29f){
          runmax[0] = fmaxf(runmax[0], fmaf(me[t], wtv[t][0], Ed0));
          runmax[1] = fmaxf(runmax[1], fmaf(me[t], wtv[t][1], Ed1));
          runmax[2] = fmaxf(runmax[2], fmaf(me[t], wtv[t][2], Ed2));
          runmax[3] = fmaxf(runmax[3], fmaf(me[t], wtv[t][3], Ed3));
        }
      }
    }
  }
  int he = *flag;
  #pragma unroll
  for (int kt = 0; kt < 4; ++kt){
    float v = runmax[kt];
    v = fmaxf(v, __shfl_xor(v, 16));
    v = fmaxf(v, __shfl_xor(v, 32));
    if (l < 16){
      int kcol = w*64 + kt*16 + l;
      float nv = fmaxf(v, 0.f);
      float outv = he ? nv : cf[m*256+kcol];
      cf[m*256+kcol] = outv;
      cfcb[m*768 + 256*(it+1) + kcol] = __float2bfloat16(outv);
    }
  }
}

// ---------------- final MFMA: ch = relu(cfc@Wch+b); feats = relu(ch@Wc2+b); sem = ch@Wsem+b
// grid 16 blocks x 256 thr; block = 16 rows x 256 cols
__global__ __launch_bounds__(256) void k_final_mfma(
  const __hip_bfloat16* __restrict__ cfcb, const __hip_bfloat16* __restrict__ WchT,
  const float* __restrict__ bch, const __hip_bfloat16* __restrict__ Wc2T,
  const float* __restrict__ bc2, const __hip_bfloat16* __restrict__ WsemT,
  const float* __restrict__ bsem, float* __restrict__ feats_out,
  float* __restrict__ sem_out)
{
  __shared__ char chs[8192];   // ch tile 16x256 bf16, XOR-swizzled
  int tid = threadIdx.x; int w = tid>>6, l = tid&63, l15 = l&15, lg = l>>4;
  int m0 = blockIdx.x*16;

  // phase 1: ch = relu(cfc @ Wch + bch), K=768
  f32x4 acc[4] = {{0,0,0,0},{0,0,0,0},{0,0,0,0},{0,0,0,0}};
  const __hip_bfloat16* Aptr = cfcb + (m0 + l15)*768;
  #pragma unroll 2
  for (int ks = 0; ks < 24; ++ks){
    int k0 = ks*32 + lg*8;
    bf16x8 Af = *reinterpret_cast<const bf16x8*>(Aptr + k0);
    #pragma unroll
    for (int nt = 0; nt < 4; ++nt){
      int col = w*64 + nt*16 + l15;
      bf16x8 Bf = *reinterpret_cast<const bf16x8*>(WchT + col*768 + k0);
      acc[nt] = __builtin_amdgcn_mfma_f32_16x16x32_bf16(Af, Bf, acc[nt], 0, 0, 0);
    }
  }
  #pragma unroll
  for (int nt = 0; nt < 4; ++nt){
    int col = w*64 + nt*16 + l15;
    float bias = bch[col];
    #pragma unroll
    for (int r = 0; r < 4; ++r){
      int row = lg*4 + r;
      float v = fmaxf(acc[nt][r] + bias, 0.f);
      int byte = ((row*256 + col)*2) ^ ((row&7)<<4);
      *reinterpret_cast<__hip_bfloat16*>(chs + byte) = __float2bfloat16(v);
    }
  }
  __syncthreads();

  // phase 2: feats = relu(ch@Wc2+bc2) [N=256], sem = ch@Wsem+bsem [N=64 padded]
  f32x4 accf[4] = {{0,0,0,0},{0,0,0,0},{0,0,0,0},{0,0,0,0}};
  f32x4 accs = {0,0,0,0};
  int cols_sem = w*16 + l15;
  #pragma unroll 2
  for (int ks = 0; ks < 8; ++ks){
    int k0 = ks*32 + lg*8;
    int byteA = (l15*512 + k0*2) ^ ((l15&7)<<4);
    bf16x8 Af = *reinterpret_cast<const bf16x8*>(chs + byteA);
    #pragma unroll
    for (int nt = 0; nt < 4; ++nt){
      int col = w*64 + nt*16 + l15;
      bf16x8 Bf = *reinterpret_cast<const bf16x8*>(Wc2T + col*256 + k0);
      accf[nt] = __builtin_amdgcn_mfma_f32_16x16x32_bf16(Af, Bf, accf[nt], 0, 0, 0);
    }
    bf16x8 Bs = *reinterpret_cast<const bf16x8*>(WsemT + cols_sem*256 + k0);
    accs = __builtin_amdgcn_mfma_f32_16x16x32_bf16(Af, Bs, accs, 0, 0, 0);
  }
  #pragma unroll
  for (int nt = 0; nt < 4; ++nt){
    int col = w*64 + nt*16 + l15;
    float bias = bc2[col];
    #pragma unroll
    for (int r = 0; r < 4; ++r){
      int row = m0 + lg*4 + r;
      feats_out[row*256 + col] = fmaxf(accf[nt][r] + bias, 0.f);
    }
  }
  if (cols_sem < 50){
    float bias = bsem[cols_sem];
    #pragma unroll
    for (int r = 0; r < 4; ++r){
      int row = m0 + lg*4 + r;
      sem_out[row*50 + cols_sem] = accs[r] + bias;
    }
  }
}

extern "C" void kernel_launch(void* const* d_in, const int* in_sizes, int n_in,
                              void* d_out, int out_size, void* d_ws, size_t ws_size,
                              hipStream_t stream)
{
  const float* pf  = (const float*)d_in[0];
  const float* gc  = (const float*)d_in[1];
  const float* gn  = (const float*)d_in[2];
  const float* Wp  = (const float*)d_in[3];
  const float* bp  = (const float*)d_in[4];
  const float* Wex = (const float*)d_in[5];
  const float* bex = (const float*)d_in[6];
  const float* Wsem= (const float*)d_in[7];
  const float* bsem= (const float*)d_in[8];
  const float* Wel = (const float*)d_in[9];
  const float* bel = (const float*)d_in[10];
  const float* Wee = (const float*)d_in[11];
  const float* bee = (const float*)d_in[12];
  const float* Wne = (const float*)d_in[13];
  const float* bne = (const float*)d_in[14];
  const float* Wch = (const float*)d_in[15];
  const float* bch = (const float*)d_in[16];
  const float* Wc2 = (const float*)d_in[17];
  const float* bc2 = (const float*)d_in[18];

  float* out = (float*)d_out;
  float* feats_out = out;             // 65536
  float* sem_out   = out + 65536;     // 12800
  float* ex_out    = out + 78336;     // 256
  float* ee_out    = out + 78592;     // 262144

  char* ws = (char*)d_ws;
  float* cf    = (float*)(ws);                       // 256 KB
  float* a_    = (float*)(ws + ( 256u<<10));         // 256 KB
  float* b2_   = (float*)(ws + ( 512u<<10));         // 256 KB
  float* b2T   = (float*)(ws + ( 768u<<10));         // 256 KB
  float* sp_   = (float*)(ws + (1024u<<10));         // 256 KB
  float* dmat  = (float*)(ws + (1280u<<10));         // 256 KB
  float* eem   = (float*)(ws + (1536u<<10));         // 1 MB
  __hip_bfloat16* WeT   = (__hip_bfloat16*)(ws + (2560u<<10)); // 256 KB
  __hip_bfloat16* cfcb  = (__hip_bfloat16*)(ws + (2816u<<10)); // 384 KB
  __hip_bfloat16* WchT  = (__hip_bfloat16*)(ws + (3200u<<10)); // 384 KB
  __hip_bfloat16* Wc2T  = (__hip_bfloat16*)(ws + (3584u<<10)); // 128 KB
  __hip_bfloat16* WsemT = (__hip_bfloat16*)(ws + (3712u<<10)); //  32 KB
  int* ok   = (int*)(ws + (3744u<<10));
  int* flag = ok + 256;

  // independent weight preps
  k_wet<<<512,256,0,stream>>>(Wne,WeT);
  k_transpose_bf16<<<48,256,0,stream>>>(Wch, WchT, 768, 256, 12);
  k_transpose_bf16<<<16,256,0,stream>>>(Wc2, Wc2T, 256, 256, 4);
  k_wsem<<<64,256,0,stream>>>(Wsem, WsemT);

  k_child<<<256,256,0,stream>>>(pf,gc,gn,Wp,bp,cf,cfcb);
  k_exists<<<256,256,0,stream>>>(cf,Wex,bex,ex_out,ok,flag);
  k_ab<<<128,256,0,stream>>>(cf,Wel,a_,b2_,b2T);
  k_ee<<<256,256,0,stream>>>(a_,b2T,bel,Wee,bee,ok,eem,ee_out,flag);
  for (int it = 0; it < 2; ++it){
    k_sd<<<128,256,0,stream>>>(cf,Wne,bne,sp_,dmat,it);
    k_fused<<<256,256,0,stream>>>(a_,bel,b2_,WeT + it*65536,sp_,dmat,eem,
                                  Wne + it*197632,cf,cfcb,flag,it);
  }
  k_final_mfma<<<16,256,0,stream>>>(cfcb,WchT,bch,Wc2T,bc2,WsemT,bsem,feats_out,sem_out);
}